// Round 9
// baseline (237.495 us; speedup 1.0000x reference)
//
#include <hip/hip_runtime.h>

#define NRAYS 16384
#define NLEV  16
#define THASH 524288
#define MAXACT 48
#define MAXPTS (NRAYS*MAXACT)
#define MBLK  1024     // k_mlp: 16 waves/block, 2 blocks/CU -> 32 waves/CU (100%)
#define MGRID 1024     // persistent grid

// clang ext-vector (layout-identical to float2) — __builtin_nontemporal_load
// requires scalar/ext-vector pointee, not HIP_vector_type.
typedef float nt2 __attribute__((ext_vector_type(2)));

// fp32 z_i exactly as np.linspace(2,6,128) fp32: z_i = fl32(2 + fl32(i*step))
__device__ __forceinline__ float zval32(int i) {
  const float step = 4.0f / 127.0f;
  return __fadd_rn(2.0f, __fmul_rn((float)i, step));
}
__device__ __forceinline__ float pcoord(float o, float d, float z) {
  return __fadd_rn(o, __fmul_rn(d, z));
}

// ---------------- kernel 1: classify rays, SH encode, compact (R0 validated) ----
__global__ __launch_bounds__(64)
void k_classify(const float* __restrict__ rays,
                float* __restrict__ sh,
                unsigned* __restrict__ counter,
                unsigned* __restrict__ rbase,
                unsigned* __restrict__ rn,
                unsigned* __restrict__ plist) {
  int r = blockIdx.x * 64 + threadIdx.x;
  if (r >= NRAYS) return;
  float ox = rays[6*r+0], oy = rays[6*r+1], oz = rays[6*r+2];
  float dx = rays[6*r+3], dy = rays[6*r+4], dz = rays[6*r+5];
  float x = dx, y = dy, z = dz;
  float xx = x*x, yy = y*y, zz = z*z, xy = x*y, yz = y*z, xz = x*z;
  float* shp = sh + 16*r;
  shp[0]  = 0.28209479177387814f;
  shp[1]  = -0.4886025119029199f * y;
  shp[2]  =  0.4886025119029199f * z;
  shp[3]  = -0.4886025119029199f * x;
  shp[4]  =  1.0925484305920792f * xy;
  shp[5]  = -1.0925484305920792f * yz;
  shp[6]  =  0.31539156525252005f * (2.0f*zz - xx - yy);
  shp[7]  = -1.0925484305920792f * xz;
  shp[8]  =  0.5462742152960396f * (xx - yy);
  shp[9]  = -0.5900435899266435f * y * (3.0f*xx - yy);
  shp[10] =  2.890611442640554f  * xy * z;
  shp[11] = -0.4570457994644658f * y * (4.0f*zz - xx - yy);
  shp[12] =  0.3731763325901154f * z * (2.0f*zz - 3.0f*xx - 3.0f*yy);
  shp[13] = -0.4570457994644658f * x * (4.0f*zz - xx - yy);
  shp[14] =  1.445305721320277f  * z * (xx - yy);
  shp[15] = -0.5900435899266435f * x * (xx - 3.0f*yy);
  // fp32 in-box prefix count (box convex, o inside => in-box samples are a prefix)
  int n = 0;
  for (int i = 0; i < 128; ++i) {
    float zi = zval32(i);
    float px = pcoord(ox, dx, zi);
    float py = pcoord(oy, dy, zi);
    float pz = pcoord(oz, dz, zi);
    bool in = (px >= -1.5f) && (px <= 1.5f) && (py >= -1.5f) && (py <= 1.5f)
           && (pz >= -1.5f) && (pz <= 1.5f);
    if (!in) break;
    ++n;
  }
  unsigned base = atomicAdd(counter, (unsigned)n);
  rbase[r] = base;
  rn[r]    = (unsigned)n;
  for (int i = 0; i < n; ++i) plist[base + i] = (unsigned)(r*128 + i);
}

// ---------------- kernel 2: cooperative tile MLP, 16 waves/tile ----------------
// Wave q computes outputs [jbase, jbase+JC) for all 64 points; FMA accumulation
// order per (point,output) is k-ascending fmaf — identical chains to the
// validated kernel, merely remapped across waves -> bit-exact.
template<int IN, int TOTOUT, int JC, bool RELU>
__device__ __forceinline__ void layer(const float* __restrict__ W, int jbase,
                                      const float* __restrict__ in,
                                      float* __restrict__ out, int lane) {
  float acc[JC];
#pragma unroll
  for (int j = 0; j < JC; ++j) acc[j] = 0.0f;
#pragma unroll 8
  for (int k = 0; k < IN; ++k) {
    float a = in[k*64 + lane];
    const float* Wk = W + k*TOTOUT + jbase;
#pragma unroll
    for (int j = 0; j < JC; ++j) acc[j] = fmaf(a, Wk[j], acc[j]);
  }
#pragma unroll
  for (int j = 0; j < JC; ++j)
    out[(jbase + j)*64 + lane] = RELU ? fmaxf(acc[j], 0.0f) : acc[j];
}

// launch_bounds(1024, 8): 8 waves/EU = 32 waves/CU = 2 blocks/CU, VGPR cap 64.
__global__ __launch_bounds__(MBLK, 8)
void k_mlp(const float* __restrict__ rays,
           const float* __restrict__ tables,
           const float* __restrict__ w_s0, const float* __restrict__ w_s1,
           const float* __restrict__ w_s2, const float* __restrict__ w_c0,
           const float* __restrict__ w_c1, const float* __restrict__ w_c2,
           const float* __restrict__ w_c3,
           const float* __restrict__ sh,
           const unsigned* __restrict__ counter,
           const unsigned* __restrict__ plist,
           float4* __restrict__ results) {
  __shared__ float bufA[64*64];
  __shared__ float bufB[64*64];
  __shared__ float sig_s[64];
  __shared__ unsigned pid_s[64];
  const int t = threadIdx.x;
  const int lane = t & 63;
  const int q = __builtin_amdgcn_readfirstlane(t >> 6);   // wave id 0..15
  const unsigned count = *counter;
  const unsigned ntiles = (count + 63u) >> 6;
  if ((unsigned)blockIdx.x >= ntiles) return;   // drop workless blocks early
  // ---- L2 warm: stream all weights (70KB) so per-layer s_loads hit warm L2 ----
  {
    float pf = 0.f;
    const float4* a;
    a = (const float4*)w_s0; for (int i = t; i < 512;  i += MBLK) pf += a[i].x;
    a = (const float4*)w_s1; for (int i = t; i < 1024; i += MBLK) pf += a[i].x;
    a = (const float4*)w_s2; for (int i = t; i < 256;  i += MBLK) pf += a[i].x;
    a = (const float4*)w_c0; for (int i = t; i < 496;  i += MBLK) pf += a[i].x;
    a = (const float4*)w_c1; for (int i = t; i < 1024; i += MBLK) pf += a[i].x;
    a = (const float4*)w_c2; for (int i = t; i < 1024; i += MBLK) pf += a[i].x;
    a = (const float4*)w_c3; for (int i = t; i < 48;   i += MBLK) pf += a[i].x;
    asm volatile("" :: "v"(pf));   // keep loads alive
  }
  const float RESF[NLEV] = {16.f,20.f,25.f,32.f,40.f,50.f,64.f,80.f,
                            101.f,128.f,161.f,203.f,256.f,322.f,406.f,512.f};
  for (unsigned tile = blockIdx.x; tile < ntiles; tile += MGRID) {
    unsigned s0 = tile << 6;
    if (t < 64) {
      unsigned s = s0 + (unsigned)t;
      pid_s[t] = (s < count) ? plist[s] : 0u;
    }
    __syncthreads();
    // ---- hash gather: wave q handles level q -> rows 2q, 2q+1 ----
    {
      unsigned pid = pid_s[lane];
      int r = (int)(pid >> 7);
      int i = (int)(pid & 127u);
      float zi = zval32(i);
      float px = pcoord(rays[6*r+0], rays[6*r+3], zi);
      float py = pcoord(rays[6*r+1], rays[6*r+4], zi);
      float pz = pcoord(rays[6*r+2], rays[6*r+5], zi);
      float xcx = fminf(fmaxf(px, -1.5f), 1.5f);
      float xcy = fminf(fmaxf(py, -1.5f), 1.5f);
      float xcz = fminf(fmaxf(pz, -1.5f), 1.5f);
      const int l = q;
      const float grid = 3.0f / RESF[l];
      float bfx = floorf(__fdiv_rn(__fadd_rn(xcx, 1.5f), grid));
      float bfy = floorf(__fdiv_rn(__fadd_rn(xcy, 1.5f), grid));
      float bfz = floorf(__fdiv_rn(__fadd_rn(xcz, 1.5f), grid));
      float vmx = __fadd_rn(__fmul_rn(bfx, grid), -1.5f);
      float vmy = __fadd_rn(__fmul_rn(bfy, grid), -1.5f);
      float vmz = __fadd_rn(__fmul_rn(bfz, grid), -1.5f);
      float wx = __fdiv_rn(__fsub_rn(xcx, vmx), grid);
      float wy = __fdiv_rn(__fsub_rn(xcy, vmy), grid);
      float wz = __fdiv_rn(__fsub_rn(xcz, vmz), grid);
      unsigned cx0 = (unsigned)(int)bfx, cy0 = (unsigned)(int)bfy, cz0 = (unsigned)(int)bfz;
      unsigned cx1 = cx0 + 1u, cy1 = cy0 + 1u, cz1 = cz0 + 1u;
      unsigned hy0 = cy0*2654435761u, hy1 = cy1*2654435761u;
      unsigned hz0 = cz0*805459861u,  hz1 = cz1*805459861u;
      const nt2* tb = (const nt2*)tables + (size_t)l*THASH;
      unsigned i000 = (cx0^hy0^hz0)&(THASH-1);
      unsigned i001 = (cx0^hy0^hz1)&(THASH-1);
      unsigned i010 = (cx0^hy1^hz0)&(THASH-1);
      unsigned i011 = (cx0^hy1^hz1)&(THASH-1);
      unsigned i100 = (cx1^hy0^hz0)&(THASH-1);
      unsigned i101 = (cx1^hy0^hz1)&(THASH-1);
      unsigned i110 = (cx1^hy1^hz0)&(THASH-1);
      unsigned i111 = (cx1^hy1^hz1)&(THASH-1);
      nt2 e000, e001, e010, e011, e100, e101, e110, e111;
      if (q >= 8) {   // wave-uniform: fine levels evict-first
        e000 = __builtin_nontemporal_load(tb + i000);
        e001 = __builtin_nontemporal_load(tb + i001);
        e010 = __builtin_nontemporal_load(tb + i010);
        e011 = __builtin_nontemporal_load(tb + i011);
        e100 = __builtin_nontemporal_load(tb + i100);
        e101 = __builtin_nontemporal_load(tb + i101);
        e110 = __builtin_nontemporal_load(tb + i110);
        e111 = __builtin_nontemporal_load(tb + i111);
      } else {        // coarse levels: heavy reuse, keep cached
        e000 = tb[i000]; e001 = tb[i001]; e010 = tb[i010]; e011 = tb[i011];
        e100 = tb[i100]; e101 = tb[i101]; e110 = tb[i110]; e111 = tb[i111];
      }
      float iwx = 1.f-wx, iwy = 1.f-wy, iwz = 1.f-wz;
      float c00a = e000.x*iwx + e100.x*wx, c00b = e000.y*iwx + e100.y*wx;
      float c01a = e001.x*iwx + e101.x*wx, c01b = e001.y*iwx + e101.y*wx;
      float c10a = e010.x*iwx + e110.x*wx, c10b = e010.y*iwx + e110.y*wx;
      float c11a = e011.x*iwx + e111.x*wx, c11b = e011.y*iwx + e111.y*wx;
      float c0a = c00a*iwy + c10a*wy, c0b = c00b*iwy + c10b*wy;
      float c1a = c01a*iwy + c11a*wy, c1b = c01b*iwy + c11b*wy;
      bufA[(2*l+0)*64 + lane] = c0a*iwz + c1a*wz;
      bufA[(2*l+1)*64 + lane] = c0b*iwz + c1b*wz;
    }
    __syncthreads();
    layer<32,64,4,true >(w_s0, q*4, bufA, bufB, lane); __syncthreads();
    layer<64,64,4,true >(w_s1, q*4, bufB, bufA, lane); __syncthreads();
    layer<64,16,1,false>(w_s2, q,   bufA, bufB, lane); __syncthreads();
    if (q == 0) sig_s[lane] = bufB[0*64 + lane];
    // color input: rows 0..15 = SH, rows 16..30 = geo (bufB rows 1..15)
    for (int idx2 = t; idx2 < 31*64; idx2 += MBLK) {
      int k = idx2 >> 6, p = idx2 & 63;
      float v;
      if (k < 16) v = sh[(pid_s[p] >> 7)*16 + k];
      else        v = bufB[(k-15)*64 + p];
      bufA[idx2] = v;
    }
    __syncthreads();
    layer<31,64,4,true >(w_c0, q*4, bufA, bufB, lane); __syncthreads();
    layer<64,64,4,true >(w_c1, q*4, bufB, bufA, lane); __syncthreads();
    layer<64,64,4,true >(w_c2, q*4, bufA, bufB, lane); __syncthreads();
    if (q < 3) layer<64,3,1,false>(w_c3, q, bufB, bufA, lane);
    __syncthreads();
    if (q == 0) {
      unsigned s = s0 + (unsigned)lane;
      if (s < count) {
        float4 res;
        res.x = sig_s[lane];
        res.y = bufA[0*64 + lane];
        res.z = bufA[1*64 + lane];
        res.w = bufA[2*64 + lane];
        results[s] = res;
      }
    }
    __syncthreads();
  }
}

// ---------------- kernel 3: composite (R0 validated per-lane version) ----------
__global__ __launch_bounds__(64)
void k_comp(const float* __restrict__ rays,
            const unsigned* __restrict__ rbase,
            const unsigned* __restrict__ rn,
            const float4* __restrict__ results,
            float* __restrict__ out) {
  int r = blockIdx.x * 64 + threadIdx.x;
  if (r >= NRAYS) return;
  float dx = rays[6*r+3], dy = rays[6*r+4], dz = rays[6*r+5];
  float dnorm = sqrtf(dx*dx + dy*dy + dz*dz);
  int n = (int)rn[r];
  unsigned base = rbase[r];
  const float step = 4.0f/127.0f;
  const float diststep = __fmul_rn(step, dnorm);   // n<=47<127: never the 1e10 tail
  float S = 0.f, ch0 = 0.f, ch1 = 0.f, ch2 = 0.f, dep = 0.f, trans = 1.f;
  for (int i = 0; i < n; ++i) {
    float4 rs = results[base + i];
    float z = zval32(i);
    float sg = fmaxf(rs.x, 0.f);
    float alpha = -expm1f(-__fmul_rn(sg, diststep));
    float w = __fmul_rn(alpha, trans);
    trans = __fmul_rn(trans, __fadd_rn(__fsub_rn(1.f, alpha), 1e-10f));
    float s0 = 1.f/(1.f + expf(-rs.y));
    float s1 = 1.f/(1.f + expf(-rs.z));
    float s2 = 1.f/(1.f + expf(-rs.w));
    S += w; ch0 += w*s0; ch1 += w*s1; ch2 += w*s2; dep += w*z;
  }
  float rem  = __fadd_rn(__fsub_rn(1.f, S), 1e-6f);
  float Stot = __fadd_rn(S, rem);
  float loss = 0.f, trans2 = 1.f;
  for (int i = 0; i < n; ++i) {
    float4 rs = results[base + i];
    float sg = fmaxf(rs.x, 0.f);
    float alpha = -expm1f(-__fmul_rn(sg, diststep));
    float w = __fmul_rn(alpha, trans2);
    trans2 = __fmul_rn(trans2, __fadd_rn(__fsub_rn(1.f, alpha), 1e-10f));
    float p = __fdiv_rn(w, Stot);
    loss += p * logf(fmaxf(p, 1e-37f));
  }
  float pl = __fdiv_rn(rem, Stot);
  loss += pl * logf(fmaxf(pl, 1e-37f));
  out[3*r+0] = ch0; out[3*r+1] = ch1; out[3*r+2] = ch2;
  out[3*NRAYS + r] = dep;
  out[4*NRAYS + r] = -loss;
}

// ---------------- launch (R0 structure) ----------------
extern "C" void kernel_launch(void* const* d_in, const int* in_sizes, int n_in,
                              void* d_out, int out_size, void* d_ws, size_t ws_size,
                              hipStream_t stream) {
  const float* rays   = (const float*)d_in[0];
  const float* tables = (const float*)d_in[1];
  const float* ws0    = (const float*)d_in[2];
  const float* ws1    = (const float*)d_in[3];
  const float* ws2    = (const float*)d_in[4];
  const float* wc0    = (const float*)d_in[5];
  const float* wc1    = (const float*)d_in[6];
  const float* wc2    = (const float*)d_in[7];
  const float* wc3    = (const float*)d_in[8];

  char* ws = (char*)d_ws;
  unsigned* counter = (unsigned*)ws;
  unsigned* rbase   = (unsigned*)(ws + 256);
  unsigned* rn      = (unsigned*)(ws + 256 + 65536);
  float*    sh      = (float*)  (ws + 256 + 131072);
  float4*   results = (float4*) (ws + 1179904);
  unsigned* plist   = (unsigned*)(ws + 1179904 + (size_t)MAXPTS*16);

  (void)hipMemsetAsync(counter, 0, 4, stream);
  k_classify<<<NRAYS/64, 64, 0, stream>>>(rays, sh, counter, rbase, rn, plist);
  k_mlp<<<MGRID, MBLK, 0, stream>>>(rays, tables, ws0, ws1, ws2,
                                    wc0, wc1, wc2, wc3, sh, counter, plist, results);
  k_comp<<<NRAYS/64, 64, 0, stream>>>(rays, rbase, rn, results, (float*)d_out);
}

// Round 10
// 185.223 us; speedup vs baseline: 1.2822x; 1.2822x over previous
//
#include <hip/hip_runtime.h>

#define NRAYS 16384
#define NLEV  16
#define THASH 524288
#define MAXACT 48
#define MAXPTS (NRAYS*MAXACT)
#define MBLK  512      // k_mlp: 8 waves
#define MGRID 1024     // persistent grid

// clang ext-vector (layout-identical to float2)
typedef float nt2 __attribute__((ext_vector_type(2)));

// fp32 z_i exactly as np.linspace(2,6,128) fp32: z_i = fl32(2 + fl32(i*step))
__device__ __forceinline__ float zval32(int i) {
  const float step = 4.0f / 127.0f;
  return __fadd_rn(2.0f, __fmul_rn((float)i, step));
}
__device__ __forceinline__ float pcoord(float o, float d, float z) {
  return __fadd_rn(o, __fmul_rn(d, z));
}

// ---------------- kernel 1: classify rays, SH encode, compact (R0 validated) ----
__global__ __launch_bounds__(64)
void k_classify(const float* __restrict__ rays,
                float* __restrict__ sh,
                unsigned* __restrict__ counter,
                unsigned* __restrict__ rbase,
                unsigned* __restrict__ rn,
                unsigned* __restrict__ plist) {
  int r = blockIdx.x * 64 + threadIdx.x;
  if (r >= NRAYS) return;
  float ox = rays[6*r+0], oy = rays[6*r+1], oz = rays[6*r+2];
  float dx = rays[6*r+3], dy = rays[6*r+4], dz = rays[6*r+5];
  float x = dx, y = dy, z = dz;
  float xx = x*x, yy = y*y, zz = z*z, xy = x*y, yz = y*z, xz = x*z;
  float* shp = sh + 16*r;
  shp[0]  = 0.28209479177387814f;
  shp[1]  = -0.4886025119029199f * y;
  shp[2]  =  0.4886025119029199f * z;
  shp[3]  = -0.4886025119029199f * x;
  shp[4]  =  1.0925484305920792f * xy;
  shp[5]  = -1.0925484305920792f * yz;
  shp[6]  =  0.31539156525252005f * (2.0f*zz - xx - yy);
  shp[7]  = -1.0925484305920792f * xz;
  shp[8]  =  0.5462742152960396f * (xx - yy);
  shp[9]  = -0.5900435899266435f * y * (3.0f*xx - yy);
  shp[10] =  2.890611442640554f  * xy * z;
  shp[11] = -0.4570457994644658f * y * (4.0f*zz - xx - yy);
  shp[12] =  0.3731763325901154f * z * (2.0f*zz - 3.0f*xx - 3.0f*yy);
  shp[13] = -0.4570457994644658f * x * (4.0f*zz - xx - yy);
  shp[14] =  1.445305721320277f  * z * (xx - yy);
  shp[15] = -0.5900435899266435f * x * (xx - 3.0f*yy);
  // fp32 in-box prefix count (box convex, o inside => in-box samples are a prefix)
  int n = 0;
  for (int i = 0; i < 128; ++i) {
    float zi = zval32(i);
    float px = pcoord(ox, dx, zi);
    float py = pcoord(oy, dy, zi);
    float pz = pcoord(oz, dz, zi);
    bool in = (px >= -1.5f) && (px <= 1.5f) && (py >= -1.5f) && (py <= 1.5f)
           && (pz >= -1.5f) && (pz <= 1.5f);
    if (!in) break;
    ++n;
  }
  unsigned base = atomicAdd(counter, (unsigned)n);
  rbase[r] = base;
  rn[r]    = (unsigned)n;
  for (int i = 0; i < n; ++i) plist[base + i] = (unsigned)(r*128 + i);
}

// ---------------- kernel 2: cooperative tile MLP ----------------
// unroll 8: 8 wave-uniform s_load weight fetches in flight. FMA order per
// output is k-ascending fmaf -> bit-exact vs validated kernel.
template<int IN, int TOTOUT, int JC, bool RELU>
__device__ __forceinline__ void layer(const float* __restrict__ W, int jbase,
                                      const float* __restrict__ in,
                                      float* __restrict__ out, int lane) {
  float acc[JC];
#pragma unroll
  for (int j = 0; j < JC; ++j) acc[j] = 0.0f;
#pragma unroll 8
  for (int k = 0; k < IN; ++k) {
    float a = in[k*64 + lane];
    const float* Wk = W + k*TOTOUT + jbase;
#pragma unroll
    for (int j = 0; j < JC; ++j) acc[j] = fmaf(a, Wk[j], acc[j]);
  }
#pragma unroll
  for (int j = 0; j < JC; ++j)
    out[(jbase + j)*64 + lane] = RELU ? fmaxf(acc[j], 0.0f) : acc[j];
}

// launch_bounds(512,4): VGPR cap 128 — room for the 16-deep forced load clause.
__global__ __launch_bounds__(MBLK, 4)
void k_mlp(const float* __restrict__ rays,
           const float* __restrict__ tables,
           const float* __restrict__ w_s0, const float* __restrict__ w_s1,
           const float* __restrict__ w_s2, const float* __restrict__ w_c0,
           const float* __restrict__ w_c1, const float* __restrict__ w_c2,
           const float* __restrict__ w_c3,
           const float* __restrict__ sh,
           const unsigned* __restrict__ counter,
           const unsigned* __restrict__ plist,
           float4* __restrict__ results) {
  __shared__ float bufA[64*64];
  __shared__ float bufB[64*64];
  __shared__ float sig_s[64];
  __shared__ unsigned pid_s[64];
  const int t = threadIdx.x;
  const int lane = t & 63;
  const int q = __builtin_amdgcn_readfirstlane(t >> 6);   // wave id 0..7
  const unsigned count = *counter;
  const unsigned ntiles = (count + 63u) >> 6;
  if ((unsigned)blockIdx.x >= ntiles) return;   // drop workless blocks early
  // ---- L2 warm: stream all weights (70KB) so per-layer s_loads hit warm L2 ----
  {
    float pf = 0.f;
    const float4* a;
    a = (const float4*)w_s0; for (int i = t; i < 512;  i += MBLK) pf += a[i].x;
    a = (const float4*)w_s1; for (int i = t; i < 1024; i += MBLK) pf += a[i].x;
    a = (const float4*)w_s2; for (int i = t; i < 256;  i += MBLK) pf += a[i].x;
    a = (const float4*)w_c0; for (int i = t; i < 496;  i += MBLK) pf += a[i].x;
    a = (const float4*)w_c1; for (int i = t; i < 1024; i += MBLK) pf += a[i].x;
    a = (const float4*)w_c2; for (int i = t; i < 1024; i += MBLK) pf += a[i].x;
    a = (const float4*)w_c3; for (int i = t; i < 48;   i += MBLK) pf += a[i].x;
    asm volatile("" :: "v"(pf));   // keep loads alive
  }
  const float RESF[NLEV] = {16.f,20.f,25.f,32.f,40.f,50.f,64.f,80.f,
                            101.f,128.f,161.f,203.f,256.f,322.f,406.f,512.f};
  for (unsigned tile = blockIdx.x; tile < ntiles; tile += MGRID) {
    unsigned s0 = tile << 6;
    if (t < 64) {
      unsigned s = s0 + (unsigned)t;
      pid_s[t] = (s < count) ? plist[s] : 0u;
    }
    __syncthreads();
    // ---- hash gather: wave q handles levels 2q, 2q+1 -> rows 4q..4q+3 ----
    // 16 loads forced into ONE in-flight clause via volatile asm (compiler's own
    // scheduling only kept ~4 outstanding -> latency-bound at 1.4 TB/s).
    {
      unsigned pid = pid_s[lane];
      int r = (int)(pid >> 7);
      int i = (int)(pid & 127u);
      float zi = zval32(i);
      float px = pcoord(rays[6*r+0], rays[6*r+3], zi);
      float py = pcoord(rays[6*r+1], rays[6*r+4], zi);
      float pz = pcoord(rays[6*r+2], rays[6*r+5], zi);
      float xcx = fminf(fmaxf(px, -1.5f), 1.5f);
      float xcy = fminf(fmaxf(py, -1.5f), 1.5f);
      float xcz = fminf(fmaxf(pz, -1.5f), 1.5f);
      float wxa[2], wya[2], wza[2];
      const nt2* ap[2][8];
#pragma unroll
      for (int li = 0; li < 2; ++li) {
        int l = 2*q + li;
        const float grid = 3.0f / RESF[l];
        float bfx = floorf(__fdiv_rn(__fadd_rn(xcx, 1.5f), grid));
        float bfy = floorf(__fdiv_rn(__fadd_rn(xcy, 1.5f), grid));
        float bfz = floorf(__fdiv_rn(__fadd_rn(xcz, 1.5f), grid));
        float vmx = __fadd_rn(__fmul_rn(bfx, grid), -1.5f);
        float vmy = __fadd_rn(__fmul_rn(bfy, grid), -1.5f);
        float vmz = __fadd_rn(__fmul_rn(bfz, grid), -1.5f);
        wxa[li] = __fdiv_rn(__fsub_rn(xcx, vmx), grid);
        wya[li] = __fdiv_rn(__fsub_rn(xcy, vmy), grid);
        wza[li] = __fdiv_rn(__fsub_rn(xcz, vmz), grid);
        unsigned cx0 = (unsigned)(int)bfx, cy0 = (unsigned)(int)bfy, cz0 = (unsigned)(int)bfz;
        unsigned cx1 = cx0 + 1u, cy1 = cy0 + 1u, cz1 = cz0 + 1u;
        unsigned hy0 = cy0*2654435761u, hy1 = cy1*2654435761u;
        unsigned hz0 = cz0*805459861u,  hz1 = cz1*805459861u;
        const nt2* tb = (const nt2*)tables + (size_t)l*THASH;
        ap[li][0] = tb + ((cx0^hy0^hz0)&(THASH-1));
        ap[li][1] = tb + ((cx0^hy0^hz1)&(THASH-1));
        ap[li][2] = tb + ((cx0^hy1^hz0)&(THASH-1));
        ap[li][3] = tb + ((cx0^hy1^hz1)&(THASH-1));
        ap[li][4] = tb + ((cx1^hy0^hz0)&(THASH-1));
        ap[li][5] = tb + ((cx1^hy0^hz1)&(THASH-1));
        ap[li][6] = tb + ((cx1^hy1^hz0)&(THASH-1));
        ap[li][7] = tb + ((cx1^hy1^hz1)&(THASH-1));
      }
      nt2 e[2][8];
#pragma unroll
      for (int li = 0; li < 2; ++li)
#pragma unroll
        for (int c = 0; c < 8; ++c)
          asm volatile("global_load_dwordx2 %0, %1, off"
                       : "=v"(e[li][c]) : "v"(ap[li][c]));
      asm volatile("s_waitcnt vmcnt(0)" ::: "memory");
      __builtin_amdgcn_sched_barrier(0);   // lesson #18: stop lerp hoisting above wait
#pragma unroll
      for (int li = 0; li < 2; ++li) {
        int l = 2*q + li;
        float wx = wxa[li], wy = wya[li], wz = wza[li];
        float iwx = 1.f-wx, iwy = 1.f-wy, iwz = 1.f-wz;
        float c00a = e[li][0].x*iwx + e[li][4].x*wx, c00b = e[li][0].y*iwx + e[li][4].y*wx;
        float c01a = e[li][1].x*iwx + e[li][5].x*wx, c01b = e[li][1].y*iwx + e[li][5].y*wx;
        float c10a = e[li][2].x*iwx + e[li][6].x*wx, c10b = e[li][2].y*iwx + e[li][6].y*wx;
        float c11a = e[li][3].x*iwx + e[li][7].x*wx, c11b = e[li][3].y*iwx + e[li][7].y*wx;
        float c0a = c00a*iwy + c10a*wy, c0b = c00b*iwy + c10b*wy;
        float c1a = c01a*iwy + c11a*wy, c1b = c01b*iwy + c11b*wy;
        bufA[(2*l+0)*64 + lane] = c0a*iwz + c1a*wz;
        bufA[(2*l+1)*64 + lane] = c0b*iwz + c1b*wz;
      }
    }
    __syncthreads();
    layer<32,64,8,true >(w_s0, q*8, bufA, bufB, lane); __syncthreads();
    layer<64,64,8,true >(w_s1, q*8, bufB, bufA, lane); __syncthreads();
    layer<64,16,2,false>(w_s2, q*2, bufA, bufB, lane); __syncthreads();
    if (q == 0) sig_s[lane] = bufB[0*64 + lane];
    // color input: rows 0..15 = SH, rows 16..30 = geo (bufB rows 1..15)
    for (int idx2 = t; idx2 < 31*64; idx2 += MBLK) {
      int k = idx2 >> 6, p = idx2 & 63;
      float v;
      if (k < 16) v = sh[(pid_s[p] >> 7)*16 + k];
      else        v = bufB[(k-15)*64 + p];
      bufA[idx2] = v;
    }
    __syncthreads();
    layer<31,64,8,true >(w_c0, q*8, bufA, bufB, lane); __syncthreads();
    layer<64,64,8,true >(w_c1, q*8, bufB, bufA, lane); __syncthreads();
    layer<64,64,8,true >(w_c2, q*8, bufA, bufB, lane); __syncthreads();
    if (q < 3) layer<64,3,1,false>(w_c3, q, bufB, bufA, lane);
    __syncthreads();
    if (q == 0) {
      unsigned s = s0 + (unsigned)lane;
      if (s < count) {
        float4 res;
        res.x = sig_s[lane];
        res.y = bufA[0*64 + lane];
        res.z = bufA[1*64 + lane];
        res.w = bufA[2*64 + lane];
        results[s] = res;
      }
    }
    __syncthreads();
  }
}

// ---------------- kernel 3: composite (R0 validated per-lane version) ----------
__global__ __launch_bounds__(64)
void k_comp(const float* __restrict__ rays,
            const unsigned* __restrict__ rbase,
            const unsigned* __restrict__ rn,
            const float4* __restrict__ results,
            float* __restrict__ out) {
  int r = blockIdx.x * 64 + threadIdx.x;
  if (r >= NRAYS) return;
  float dx = rays[6*r+3], dy = rays[6*r+4], dz = rays[6*r+5];
  float dnorm = sqrtf(dx*dx + dy*dy + dz*dz);
  int n = (int)rn[r];
  unsigned base = rbase[r];
  const float step = 4.0f/127.0f;
  const float diststep = __fmul_rn(step, dnorm);   // n<=47<127: never the 1e10 tail
  float S = 0.f, ch0 = 0.f, ch1 = 0.f, ch2 = 0.f, dep = 0.f, trans = 1.f;
  for (int i = 0; i < n; ++i) {
    float4 rs = results[base + i];
    float z = zval32(i);
    float sg = fmaxf(rs.x, 0.f);
    float alpha = -expm1f(-__fmul_rn(sg, diststep));
    float w = __fmul_rn(alpha, trans);
    trans = __fmul_rn(trans, __fadd_rn(__fsub_rn(1.f, alpha), 1e-10f));
    float s0 = 1.f/(1.f + expf(-rs.y));
    float s1 = 1.f/(1.f + expf(-rs.z));
    float s2 = 1.f/(1.f + expf(-rs.w));
    S += w; ch0 += w*s0; ch1 += w*s1; ch2 += w*s2; dep += w*z;
  }
  float rem  = __fadd_rn(__fsub_rn(1.f, S), 1e-6f);
  float Stot = __fadd_rn(S, rem);
  float loss = 0.f, trans2 = 1.f;
  for (int i = 0; i < n; ++i) {
    float4 rs = results[base + i];
    float sg = fmaxf(rs.x, 0.f);
    float alpha = -expm1f(-__fmul_rn(sg, diststep));
    float w = __fmul_rn(alpha, trans2);
    trans2 = __fmul_rn(trans2, __fadd_rn(__fsub_rn(1.f, alpha), 1e-10f));
    float p = __fdiv_rn(w, Stot);
    loss += p * logf(fmaxf(p, 1e-37f));
  }
  float pl = __fdiv_rn(rem, Stot);
  loss += pl * logf(fmaxf(pl, 1e-37f));
  out[3*r+0] = ch0; out[3*r+1] = ch1; out[3*r+2] = ch2;
  out[3*NRAYS + r] = dep;
  out[4*NRAYS + r] = -loss;
}

// ---------------- launch (R0 structure) ----------------
extern "C" void kernel_launch(void* const* d_in, const int* in_sizes, int n_in,
                              void* d_out, int out_size, void* d_ws, size_t ws_size,
                              hipStream_t stream) {
  const float* rays   = (const float*)d_in[0];
  const float* tables = (const float*)d_in[1];
  const float* ws0    = (const float*)d_in[2];
  const float* ws1    = (const float*)d_in[3];
  const float* ws2    = (const float*)d_in[4];
  const float* wc0    = (const float*)d_in[5];
  const float* wc1    = (const float*)d_in[6];
  const float* wc2    = (const float*)d_in[7];
  const float* wc3    = (const float*)d_in[8];

  char* ws = (char*)d_ws;
  unsigned* counter = (unsigned*)ws;
  unsigned* rbase   = (unsigned*)(ws + 256);
  unsigned* rn      = (unsigned*)(ws + 256 + 65536);
  float*    sh      = (float*)  (ws + 256 + 131072);
  float4*   results = (float4*) (ws + 1179904);
  unsigned* plist   = (unsigned*)(ws + 1179904 + (size_t)MAXPTS*16);

  (void)hipMemsetAsync(counter, 0, 4, stream);
  k_classify<<<NRAYS/64, 64, 0, stream>>>(rays, sh, counter, rbase, rn, plist);
  k_mlp<<<MGRID, MBLK, 0, stream>>>(rays, tables, ws0, ws1, ws2,
                                    wc0, wc1, wc2, wc3, sh, counter, plist, results);
  k_comp<<<NRAYS/64, 64, 0, stream>>>(rays, rbase, rn, results, (float*)d_out);
}